// Round 4
// baseline (786.103 us; speedup 1.0000x reference)
//
#include <hip/hip_runtime.h>
#include <stdint.h>

#define B_DIM 4
#define S_DIM 2048
#define D_DIM 2048
#define H_DIM 16
#define M_ROWS (B_DIM * S_DIM)   // 8192
#define CONCAT_LD 4096
#define NCHUNK 32
#define CHLEN (S_DIM / NCHUNK)   // 64

#define BM 128
#define BN 64
#define BK 64

typedef __attribute__((ext_vector_type(8))) __bf16 bf16x8;
typedef __attribute__((ext_vector_type(4))) float f32x4;

__device__ inline unsigned short f2bf(float f) {
  union { float f; unsigned u; } x; x.f = f;
  unsigned r = x.u + 0x7fffu + ((x.u >> 16) & 1u);
  return (unsigned short)(r >> 16);
}
__device__ inline float bf2f(unsigned short s) {
  union { unsigned u; float f; } x; x.u = ((unsigned)s) << 16;
  return x.f;
}

// ---- fused: x fp32 -> bf16 into concat[:,0:2048]  AND  logits = x @ W_att ----
__global__ __launch_bounds__(256) void xconv_logits_kernel(
    const float* __restrict__ x, const float* __restrict__ Watt,
    unsigned short* __restrict__ concat, float* __restrict__ logits) {
  int row = blockIdx.x, t = threadIdx.x;
  const float* xr = x + (size_t)row * D_DIM;
  unsigned short* cr = concat + (size_t)row * CONCAT_LD;
  float p[H_DIM];
#pragma unroll
  for (int h = 0; h < H_DIM; ++h) p[h] = 0.f;
#pragma unroll
  for (int i = 0; i < 8; ++i) {
    int k = t + i * 256;
    float xv = xr[k];
    cr[k] = f2bf(xv);
    const float* wr = Watt + (size_t)k * H_DIM;
#pragma unroll
    for (int h = 0; h < H_DIM; ++h) p[h] += xv * wr[h];
  }
  __shared__ float red[4][H_DIM];
  int l = t & 63, w = t >> 6;
#pragma unroll
  for (int h = 0; h < H_DIM; ++h) {
    float v = p[h];
    for (int off = 32; off; off >>= 1) v += __shfl_down(v, off);
    if (l == 0) red[w][h] = v;
  }
  __syncthreads();
  if (t < H_DIM)
    logits[(size_t)row * H_DIM + t] = red[0][t] + red[1][t] + red[2][t] + red[3][t];
}

// ---- fp32 [R][C] -> bf16 transposed [C][R] ----
__global__ __launch_bounds__(256) void transpose_conv_kernel(
    const float* __restrict__ src, unsigned short* __restrict__ dst, int R, int C) {
  __shared__ float tile[32][33];
  int c0 = blockIdx.x * 32, r0 = blockIdx.y * 32;
  int tx = threadIdx.x & 31, ty = threadIdx.x >> 5;
#pragma unroll
  for (int i = 0; i < 32; i += 8)
    tile[ty + i][tx] = src[(size_t)(r0 + ty + i) * C + c0 + tx];
  __syncthreads();
#pragma unroll
  for (int i = 0; i < 32; i += 8)
    dst[(size_t)(c0 + ty + i) * R + r0 + tx] = f2bf(tile[tx][ty + i]);
}

// ---- per (b,h): max over s, then coef = w/(w*(s+1)+1e-30), w=exp((lg-mx)*T) ----
__global__ __launch_bounds__(256) void coef_kernel(
    const float* __restrict__ logits, const float* __restrict__ temp, float* __restrict__ coef) {
  int b = blockIdx.x >> 4, h = blockIdx.x & 15;
  int t = threadIdx.x;
  const float* lg = logits + (size_t)b * S_DIM * H_DIM + h;
  float mx = -1e30f;
  for (int s = t; s < S_DIM; s += 256) mx = fmaxf(mx, lg[(size_t)s * H_DIM]);
  for (int off = 32; off; off >>= 1) mx = fmaxf(mx, __shfl_down(mx, off));
  __shared__ float red[4];
  if ((t & 63) == 0) red[t >> 6] = mx;
  __syncthreads();
  mx = fmaxf(fmaxf(red[0], red[1]), fmaxf(red[2], red[3]));
  float T = temp[h];
  float* cf = coef + (size_t)b * S_DIM * H_DIM + h;
  for (int s = t; s < S_DIM; s += 256) {
    float w = expf((lg[(size_t)s * H_DIM] - mx) * T);
    cf[(size_t)s * H_DIM] = w / (w * (float)(s + 1) + 1e-30f);
  }
}

// ---- GEMM: C[M,N] = A[M,K](bf16,lda) * Bt[N,K](bf16,ldb)^T ----
// BM=128, BN=64, BK=64; 4 waves, 64x32 wave tile (4x2 accs) -> 32 AGPRs/wave
// for ~5 waves/SIMD occupancy. LDS XOR swizzle (chunk c of row r at slot
// c^(r&7)) -> conflict-free ds_read_b128 (verified 0 conflicts R2/R3).
// MODE 1: out bf16, no bias            (v = x @ W_values)
// MODE 2: out bf16, bias=vector[b][n]  (op = pooled @ W_op + vector)
// MODE 3: out bf16, bias[n] + relu     (h1 = relu(concat @ ff1 + b))
// MODE 4: out fp32, bias[n]+relu+resid (res = relu(h1 @ ff2 + b) + x)
template <int MODE>
__global__ __launch_bounds__(256, 4) void gemm_bt_kernel(
    const unsigned short* __restrict__ A, int lda,
    const unsigned short* __restrict__ Bt, int ldb, int K,
    void* __restrict__ outp, int ldo,
    const float* __restrict__ bias, const float* __restrict__ resid) {
  __shared__ unsigned short As[BM * BK];
  __shared__ unsigned short Bs[BN * BK];
  const int t = threadIdx.x;
  const int w = t >> 6, l = t & 63;
  const int wm = w & 1, wn = w >> 1;
  const int q = l >> 4, ln = l & 15;

  // XCD-aware block swizzle (grid fixed at (32,64) for all four GEMMs).
  const int L = blockIdx.y * 32 + blockIdx.x;
  const int xcd = L & 7;
  const int W = L >> 3;
  const int bx = W & 31;
  const int by = (W >> 5) * 8 + xcd;
  const int m0 = by * BM, n0 = bx * BN;

  f32x4 acc[4][2];
#pragma unroll
  for (int i = 0; i < 4; ++i)
#pragma unroll
    for (int j = 0; j < 2; ++j) acc[i][j] = {0.f, 0.f, 0.f, 0.f};

  for (int k0 = 0; k0 < K; k0 += BK) {
    __syncthreads();
    // A: 128 rows x 8 chunks = 1024 chunks, 4 per thread
#pragma unroll
    for (int r = 0; r < 4; ++r) {
      int s = r * 256 + t;
      int row = s >> 3;
      int ch = (s & 7) ^ (row & 7);
      const unsigned short* ga = A + (size_t)(m0 + row) * lda + k0 + ch * 8;
      __builtin_amdgcn_global_load_lds(
          (const __attribute__((address_space(1))) void*)ga,
          (__attribute__((address_space(3))) void*)(As + (r * 256 + w * 64) * 8), 16, 0, 0);
    }
    // B: 64 rows x 8 chunks = 512 chunks, 2 per thread
#pragma unroll
    for (int r = 0; r < 2; ++r) {
      int s = r * 256 + t;
      int row = s >> 3;
      int ch = (s & 7) ^ (row & 7);
      const unsigned short* gb = Bt + (size_t)(n0 + row) * ldb + k0 + ch * 8;
      __builtin_amdgcn_global_load_lds(
          (const __attribute__((address_space(1))) void*)gb,
          (__attribute__((address_space(3))) void*)(Bs + (r * 256 + w * 64) * 8), 16, 0, 0);
    }
    __syncthreads();
#pragma unroll
    for (int h = 0; h < 2; ++h) {
      bf16x8 af[4], bfr[2];
#pragma unroll
      for (int mt = 0; mt < 4; ++mt) {
        int ar = wm * 64 + mt * 16 + ln;
        af[mt] = *(const bf16x8*)&As[ar * BK + (((h * 4 + q) ^ (ar & 7)) * 8)];
      }
#pragma unroll
      for (int nt = 0; nt < 2; ++nt) {
        int br = wn * 32 + nt * 16 + ln;
        bfr[nt] = *(const bf16x8*)&Bs[br * BK + (((h * 4 + q) ^ (br & 7)) * 8)];
      }
#pragma unroll
      for (int mt = 0; mt < 4; ++mt)
#pragma unroll
        for (int nt = 0; nt < 2; ++nt)
          acc[mt][nt] = __builtin_amdgcn_mfma_f32_16x16x32_bf16(af[mt], bfr[nt], acc[mt][nt], 0, 0, 0);
    }
  }

#pragma unroll
  for (int mt = 0; mt < 4; ++mt) {
#pragma unroll
    for (int i = 0; i < 4; ++i) {
      int row = m0 + wm * 64 + mt * 16 + q * 4 + i;
#pragma unroll
      for (int nt = 0; nt < 2; ++nt) {
        int col = n0 + wn * 32 + nt * 16 + ln;
        float vv = acc[mt][nt][i];
        if (MODE == 2) vv += bias[(size_t)(row >> 11) * 2048 + col];
        if (MODE == 3) { vv += bias[col]; vv = fmaxf(vv, 0.f); }
        if (MODE == 4) {
          vv += bias[col]; vv = fmaxf(vv, 0.f);
          vv += resid[(size_t)row * 2048 + col];
          ((float*)outp)[(size_t)row * ldo + col] = vv;
        } else {
          ((unsigned short*)outp)[(size_t)row * ldo + col] = f2bf(vv);
        }
      }
    }
  }
}

// ---- chunked scan over S of v[b][s][c], fused coef multiply ----
__global__ __launch_bounds__(256) void scan_partial_kernel(
    const unsigned short* __restrict__ v, float* __restrict__ csum) {
  int c = blockIdx.x * 256 + threadIdx.x;
  int chunk = blockIdx.y, b = blockIdx.z;
  const unsigned short* p = v + ((size_t)(b * S_DIM + chunk * CHLEN)) * D_DIM + c;
  float s = 0.f;
#pragma unroll 4
  for (int i = 0; i < CHLEN; ++i) s += bf2f(p[(size_t)i * D_DIM]);
  csum[((size_t)b * NCHUNK + chunk) * D_DIM + c] = s;
}

__global__ __launch_bounds__(256) void scan_offsets_kernel(float* __restrict__ csum) {
  int c = blockIdx.x * 256 + threadIdx.x;
  int b = blockIdx.y;
  float run = 0.f;
  float* p = csum + (size_t)b * NCHUNK * D_DIM + c;
  for (int ch = 0; ch < NCHUNK; ++ch) {
    float tv = p[(size_t)ch * D_DIM];
    p[(size_t)ch * D_DIM] = run;
    run += tv;
  }
}

__global__ __launch_bounds__(256) void scan_apply_kernel(
    const unsigned short* __restrict__ v, const float* __restrict__ csum,
    const float* __restrict__ coef, unsigned short* __restrict__ pooled) {
  int c = blockIdx.x * 256 + threadIdx.x;
  int chunk = blockIdx.y, b = blockIdx.z;
  int h = c >> 7;
  float run = csum[((size_t)b * NCHUNK + chunk) * D_DIM + c];
  size_t base = ((size_t)(b * S_DIM + chunk * CHLEN)) * D_DIM + c;
  const float* cf = coef + ((size_t)b * S_DIM + chunk * CHLEN) * H_DIM + h;
#pragma unroll 4
  for (int i = 0; i < CHLEN; ++i) {
    run += bf2f(v[base + (size_t)i * D_DIM]);
    pooled[base + (size_t)i * D_DIM] = f2bf(cf[(size_t)i * H_DIM] * run);
  }
}

// ---- in-place LayerNorm on d_out rows ----
__global__ __launch_bounds__(256) void ln_kernel(
    float* __restrict__ out, const float* __restrict__ gamma, const float* __restrict__ beta) {
  int row = blockIdx.x, t = threadIdx.x;
  float* pr = out + (size_t)row * D_DIM;
  float vals[8];
  float s = 0.f;
#pragma unroll
  for (int i = 0; i < 8; ++i) { vals[i] = pr[t + i * 256]; s += vals[i]; }
  __shared__ float red[4];
  for (int off = 32; off; off >>= 1) s += __shfl_down(s, off);
  if ((t & 63) == 0) red[t >> 6] = s;
  __syncthreads();
  float mean = (red[0] + red[1] + red[2] + red[3]) * (1.f / D_DIM);
  __syncthreads();
  float c2 = 0.f;
#pragma unroll
  for (int i = 0; i < 8; ++i) { float c = vals[i] - mean; c2 += c * c; }
  for (int off = 32; off; off >>= 1) c2 += __shfl_down(c2, off);
  if ((t & 63) == 0) red[t >> 6] = c2;
  __syncthreads();
  float var = (red[0] + red[1] + red[2] + red[3]) * (1.f / D_DIM);
  float rstd = rsqrtf(var + 1e-6f);
#pragma unroll
  for (int i = 0; i < 8; ++i) {
    int col = t + i * 256;
    pr[col] = (vals[i] - mean) * rstd * gamma[col] + beta[col];
  }
}

extern "C" void kernel_launch(void* const* d_in, const int* in_sizes, int n_in,
                              void* d_out, int out_size, void* d_ws, size_t ws_size,
                              hipStream_t stream) {
  const float* x      = (const float*)d_in[0];
  const float* vector = (const float*)d_in[1];
  const float* W_att  = (const float*)d_in[2];
  const float* temp   = (const float*)d_in[3];
  const float* W_val  = (const float*)d_in[4];
  const float* W_op   = (const float*)d_in[5];
  const float* ff1    = (const float*)d_in[6];
  const float* ff1_b  = (const float*)d_in[7];
  const float* ff2    = (const float*)d_in[8];
  const float* ff2_b  = (const float*)d_in[9];
  const float* gamma  = (const float*)d_in[10];
  const float* beta   = (const float*)d_in[11];
  float* out = (float*)d_out;

  char* ws = (char*)d_ws;
  auto alloc = [&](size_t bytes) {
    char* p = ws; ws += (bytes + 255) & ~(size_t)255; return p;
  };
  unsigned short* concat = (unsigned short*)alloc((size_t)M_ROWS * CONCAT_LD * 2);
  unsigned short* wv_t   = (unsigned short*)alloc((size_t)2048 * 2048 * 2);
  unsigned short* wop_t  = (unsigned short*)alloc((size_t)2048 * 2048 * 2);
  unsigned short* ff1_t  = (unsigned short*)alloc((size_t)2048 * 4096 * 2);
  unsigned short* ff2_t  = (unsigned short*)alloc((size_t)2048 * 2048 * 2);
  unsigned short* vbuf   = (unsigned short*)alloc((size_t)M_ROWS * 2048 * 2);
  unsigned short* pooled = (unsigned short*)alloc((size_t)M_ROWS * 2048 * 2);
  unsigned short* h1     = (unsigned short*)alloc((size_t)M_ROWS * 2048 * 2);
  float* logits = (float*)alloc((size_t)M_ROWS * H_DIM * 4);
  float* coef   = (float*)alloc((size_t)M_ROWS * H_DIM * 4);
  float* csum   = (float*)alloc((size_t)B_DIM * NCHUNK * D_DIM * 4);

  xconv_logits_kernel<<<M_ROWS, 256, 0, stream>>>(x, W_att, concat, logits);
  transpose_conv_kernel<<<dim3(64, 64), 256, 0, stream>>>(W_val, wv_t, 2048, 2048);
  transpose_conv_kernel<<<dim3(64, 64), 256, 0, stream>>>(W_op, wop_t, 2048, 2048);
  transpose_conv_kernel<<<dim3(64, 128), 256, 0, stream>>>(ff1, ff1_t, 4096, 2048);
  transpose_conv_kernel<<<dim3(64, 64), 256, 0, stream>>>(ff2, ff2_t, 2048, 2048);
  coef_kernel<<<B_DIM * H_DIM, 256, 0, stream>>>(logits, temp, coef);
  // v = x @ W_values
  gemm_bt_kernel<1><<<dim3(2048 / BN, M_ROWS / BM), 256, 0, stream>>>(
      concat, CONCAT_LD, wv_t, 2048, 2048, vbuf, 2048, nullptr, nullptr);
  scan_partial_kernel<<<dim3(8, NCHUNK, B_DIM), 256, 0, stream>>>(vbuf, csum);
  scan_offsets_kernel<<<dim3(8, B_DIM), 256, 0, stream>>>(csum);
  scan_apply_kernel<<<dim3(8, NCHUNK, B_DIM), 256, 0, stream>>>(vbuf, csum, coef, pooled);
  // op = pooled @ W_op + vector -> concat[:, 2048:4096]
  gemm_bt_kernel<2><<<dim3(2048 / BN, M_ROWS / BM), 256, 0, stream>>>(
      pooled, 2048, wop_t, 2048, 2048, concat + 2048, CONCAT_LD, vector, nullptr);
  // h1 = relu(concat @ ff1 + ff1_b)
  gemm_bt_kernel<3><<<dim3(2048 / BN, M_ROWS / BM), 256, 0, stream>>>(
      concat, CONCAT_LD, ff1_t, 4096, 4096, h1, 2048, ff1_b, nullptr);
  // out = relu(h1 @ ff2 + ff2_b) + x
  gemm_bt_kernel<4><<<dim3(2048 / BN, M_ROWS / BM), 256, 0, stream>>>(
      h1, 2048, ff2_t, 2048, 2048, out, 2048, ff2_b, x);
  ln_kernel<<<M_ROWS, 256, 0, stream>>>(out, gamma, beta);
}

// Round 5
// 737.866 us; speedup vs baseline: 1.0654x; 1.0654x over previous
//
#include <hip/hip_runtime.h>
#include <stdint.h>

#define B_DIM 4
#define S_DIM 2048
#define D_DIM 2048
#define H_DIM 16
#define M_ROWS (B_DIM * S_DIM)   // 8192
#define CONCAT_LD 4096
#define NCHUNK 32
#define CHLEN (S_DIM / NCHUNK)   // 64

#define BM 128
#define BN 128
#define BK 64

typedef __attribute__((ext_vector_type(8))) __bf16 bf16x8;
typedef __attribute__((ext_vector_type(4))) float f32x4;

__device__ inline unsigned short f2bf(float f) {
  union { float f; unsigned u; } x; x.f = f;
  unsigned r = x.u + 0x7fffu + ((x.u >> 16) & 1u);
  return (unsigned short)(r >> 16);
}
__device__ inline float bf2f(unsigned short s) {
  union { unsigned u; float f; } x; x.u = ((unsigned)s) << 16;
  return x.f;
}

// ---- fused: x fp32 -> bf16 into concat[:,0:2048]  AND  logits = x @ W_att ----
__global__ __launch_bounds__(256) void xconv_logits_kernel(
    const float* __restrict__ x, const float* __restrict__ Watt,
    unsigned short* __restrict__ concat, float* __restrict__ logits) {
  int row = blockIdx.x, t = threadIdx.x;
  const float* xr = x + (size_t)row * D_DIM;
  unsigned short* cr = concat + (size_t)row * CONCAT_LD;
  float p[H_DIM];
#pragma unroll
  for (int h = 0; h < H_DIM; ++h) p[h] = 0.f;
#pragma unroll
  for (int i = 0; i < 8; ++i) {
    int k = t + i * 256;
    float xv = xr[k];
    cr[k] = f2bf(xv);
    const float* wr = Watt + (size_t)k * H_DIM;
#pragma unroll
    for (int h = 0; h < H_DIM; ++h) p[h] += xv * wr[h];
  }
  __shared__ float red[4][H_DIM];
  int l = t & 63, w = t >> 6;
#pragma unroll
  for (int h = 0; h < H_DIM; ++h) {
    float v = p[h];
    for (int off = 32; off; off >>= 1) v += __shfl_down(v, off);
    if (l == 0) red[w][h] = v;
  }
  __syncthreads();
  if (t < H_DIM)
    logits[(size_t)row * H_DIM + t] = red[0][t] + red[1][t] + red[2][t] + red[3][t];
}

// ---- fp32 [R][C] -> bf16 transposed [C][R], dst leading dim ldd ----
__global__ __launch_bounds__(256) void transpose_conv_kernel(
    const float* __restrict__ src, unsigned short* __restrict__ dst,
    int R, int C, int ldd) {
  __shared__ float tile[32][33];
  int c0 = blockIdx.x * 32, r0 = blockIdx.y * 32;
  int tx = threadIdx.x & 31, ty = threadIdx.x >> 5;
#pragma unroll
  for (int i = 0; i < 32; i += 8)
    tile[ty + i][tx] = src[(size_t)(r0 + ty + i) * C + c0 + tx];
  __syncthreads();
#pragma unroll
  for (int i = 0; i < 32; i += 8)
    dst[(size_t)(c0 + ty + i) * ldd + r0 + tx] = f2bf(tile[tx][ty + i]);
}

// ---- fp32 -> bf16 plain convert (contiguous) ----
__global__ __launch_bounds__(256) void convert_kernel(
    const float* __restrict__ src, unsigned short* __restrict__ dst) {
  int idx = (blockIdx.x * 256 + threadIdx.x) * 4;
  const float4 v = *(const float4*)(src + idx);
  ushort4 o;
  o.x = f2bf(v.x); o.y = f2bf(v.y); o.z = f2bf(v.z); o.w = f2bf(v.w);
  *(ushort4*)(dst + idx) = o;
}

// ---- per (b,h): max over s, then coef = w/(w*(s+1)+1e-30), w=exp((lg-mx)*T) ----
__global__ __launch_bounds__(256) void coef_kernel(
    const float* __restrict__ logits, const float* __restrict__ temp, float* __restrict__ coef) {
  int b = blockIdx.x >> 4, h = blockIdx.x & 15;
  int t = threadIdx.x;
  const float* lg = logits + (size_t)b * S_DIM * H_DIM + h;
  float mx = -1e30f;
  for (int s = t; s < S_DIM; s += 256) mx = fmaxf(mx, lg[(size_t)s * H_DIM]);
  for (int off = 32; off; off >>= 1) mx = fmaxf(mx, __shfl_down(mx, off));
  __shared__ float red[4];
  if ((t & 63) == 0) red[t >> 6] = mx;
  __syncthreads();
  mx = fmaxf(fmaxf(red[0], red[1]), fmaxf(red[2], red[3]));
  float T = temp[h];
  float* cf = coef + (size_t)b * S_DIM * H_DIM + h;
  for (int s = t; s < S_DIM; s += 256) {
    float w = expf((lg[(size_t)s * H_DIM] - mx) * T);
    cf[(size_t)s * H_DIM] = w / (w * (float)(s + 1) + 1e-30f);
  }
}

// ---- bias2 = vector @ F1b (+ ff1_b), partial over j-segments then reduce ----
__global__ __launch_bounds__(256) void bias2_partial_kernel(
    const float* __restrict__ vector, const float* __restrict__ ff1,
    float* __restrict__ part) {
  int n = blockIdx.x * 256 + threadIdx.x;
  int seg = blockIdx.y, b = blockIdx.z;
  const float* vr = vector + (size_t)b * 2048 + seg * 128;
  const float* fr = ff1 + (size_t)(2048 + seg * 128) * 2048 + n;
  float acc = 0.f;
#pragma unroll 8
  for (int j = 0; j < 128; ++j) acc += vr[j] * fr[(size_t)j * 2048];
  part[((size_t)seg * 4 + b) * 2048 + n] = acc;
}

__global__ __launch_bounds__(256) void bias2_reduce_kernel(
    const float* __restrict__ part, const float* __restrict__ ff1_b,
    float* __restrict__ bias2) {
  int n = blockIdx.x * 256 + threadIdx.x;
  int b = blockIdx.y;
  float acc = ff1_b[n];
#pragma unroll
  for (int s = 0; s < 16; ++s) acc += part[((size_t)s * 4 + b) * 2048 + n];
  bias2[(size_t)b * 2048 + n] = acc;
}

// ---- GEMM: C[M,N] = A[M,K](bf16,lda) * Bt[N,K](bf16,ldb)^T ----
// BM=128, BN=128, BK=64 (R3 config: ff1 @ 165.7us, FETCH 164MB, 0 conflicts).
// LDS XOR swizzle: chunk c of row r at slot c^(r&7) -> conflict-free ds_read_b128.
// MODE 1: out bf16, no bias            (v GEMM, Wc GEMM)
// MODE 2: out bf16, bias2[b][n] + relu (ff1' = relu(concat@[F1a;Wc] + bias2))
// MODE 4: out fp32, bias[n]+relu+resid (res = relu(h1 @ ff2 + b) + x)
template <int MODE>
__global__ __launch_bounds__(256) void gemm_bt_kernel(
    const unsigned short* __restrict__ A, int lda,
    const unsigned short* __restrict__ Bt, int ldb, int K,
    void* __restrict__ outp, int ldo,
    const float* __restrict__ bias, const float* __restrict__ resid) {
  __shared__ unsigned short As[BM * BK];
  __shared__ unsigned short Bs[BN * BK];
  const int t = threadIdx.x;
  const int w = t >> 6, l = t & 63;
  const int wm = w & 1, wn = w >> 1;
  const int q = l >> 4, ln = l & 15;

  // XCD-aware block swizzle (gridDim.x == 16, gridDim.y multiple of 8).
  const int L = blockIdx.y * 16 + blockIdx.x;
  const int xcd = L & 7;
  const int W = L >> 3;
  const int bx = W & 15;
  const int by = (W >> 4) * 8 + xcd;
  const int m0 = by * BM, n0 = bx * BN;

  f32x4 acc[4][4];
#pragma unroll
  for (int i = 0; i < 4; ++i)
#pragma unroll
    for (int j = 0; j < 4; ++j) acc[i][j] = {0.f, 0.f, 0.f, 0.f};

  for (int k0 = 0; k0 < K; k0 += BK) {
    __syncthreads();
#pragma unroll
    for (int r = 0; r < 4; ++r) {
      int s = r * 256 + t;
      int row = s >> 3;
      int ch = (s & 7) ^ (row & 7);
      const unsigned short* ga = A + (size_t)(m0 + row) * lda + k0 + ch * 8;
      __builtin_amdgcn_global_load_lds(
          (const __attribute__((address_space(1))) void*)ga,
          (__attribute__((address_space(3))) void*)(As + (r * 256 + w * 64) * 8), 16, 0, 0);
      const unsigned short* gb = Bt + (size_t)(n0 + row) * ldb + k0 + ch * 8;
      __builtin_amdgcn_global_load_lds(
          (const __attribute__((address_space(1))) void*)gb,
          (__attribute__((address_space(3))) void*)(Bs + (r * 256 + w * 64) * 8), 16, 0, 0);
    }
    __syncthreads();
#pragma unroll
    for (int h = 0; h < 2; ++h) {
      bf16x8 af[4], bfr[4];
#pragma unroll
      for (int mt = 0; mt < 4; ++mt) {
        int ar = wm * 64 + mt * 16 + ln;
        af[mt] = *(const bf16x8*)&As[ar * BK + (((h * 4 + q) ^ (ar & 7)) * 8)];
      }
#pragma unroll
      for (int nt = 0; nt < 4; ++nt) {
        int br = wn * 64 + nt * 16 + ln;
        bfr[nt] = *(const bf16x8*)&Bs[br * BK + (((h * 4 + q) ^ (br & 7)) * 8)];
      }
#pragma unroll
      for (int mt = 0; mt < 4; ++mt)
#pragma unroll
        for (int nt = 0; nt < 4; ++nt)
          acc[mt][nt] = __builtin_amdgcn_mfma_f32_16x16x32_bf16(af[mt], bfr[nt], acc[mt][nt], 0, 0, 0);
    }
  }

#pragma unroll
  for (int mt = 0; mt < 4; ++mt) {
#pragma unroll
    for (int i = 0; i < 4; ++i) {
      int row = m0 + wm * 64 + mt * 16 + q * 4 + i;
#pragma unroll
      for (int nt = 0; nt < 4; ++nt) {
        int col = n0 + wn * 64 + nt * 16 + ln;
        float vv = acc[mt][nt][i];
        if (MODE == 2) { vv += bias[(size_t)(row >> 11) * 2048 + col]; vv = fmaxf(vv, 0.f); }
        if (MODE == 4) {
          vv += bias[col]; vv = fmaxf(vv, 0.f);
          vv += resid[(size_t)row * 2048 + col];
          ((float*)outp)[(size_t)row * ldo + col] = vv;
        } else {
          ((unsigned short*)outp)[(size_t)row * ldo + col] = f2bf(vv);
        }
      }
    }
  }
}

// ---- chunked scan over S of v[b][s][c], fused coef multiply ----
__global__ __launch_bounds__(256) void scan_partial_kernel(
    const unsigned short* __restrict__ v, float* __restrict__ csum) {
  int c = blockIdx.x * 256 + threadIdx.x;
  int chunk = blockIdx.y, b = blockIdx.z;
  const unsigned short* p = v + ((size_t)(b * S_DIM + chunk * CHLEN)) * D_DIM + c;
  float s = 0.f;
#pragma unroll 4
  for (int i = 0; i < CHLEN; ++i) s += bf2f(p[(size_t)i * D_DIM]);
  csum[((size_t)b * NCHUNK + chunk) * D_DIM + c] = s;
}

__global__ __launch_bounds__(256) void scan_offsets_kernel(float* __restrict__ csum) {
  int c = blockIdx.x * 256 + threadIdx.x;
  int b = blockIdx.y;
  float run = 0.f;
  float* p = csum + (size_t)b * NCHUNK * D_DIM + c;
  for (int ch = 0; ch < NCHUNK; ++ch) {
    float tv = p[(size_t)ch * D_DIM];
    p[(size_t)ch * D_DIM] = run;
    run += tv;
  }
}

// writes pooled directly into concat[:, 2048:4096] (ld 4096)
__global__ __launch_bounds__(256) void scan_apply_kernel(
    const unsigned short* __restrict__ v, const float* __restrict__ csum,
    const float* __restrict__ coef, unsigned short* __restrict__ pooled_out) {
  int c = blockIdx.x * 256 + threadIdx.x;
  int chunk = blockIdx.y, b = blockIdx.z;
  int h = c >> 7;
  int row0 = b * S_DIM + chunk * CHLEN;
  float run = csum[((size_t)b * NCHUNK + chunk) * D_DIM + c];
  const unsigned short* vp = v + (size_t)row0 * D_DIM + c;
  unsigned short* po = pooled_out + (size_t)row0 * CONCAT_LD + c;
  const float* cf = coef + (size_t)row0 * H_DIM + h;
#pragma unroll 4
  for (int i = 0; i < CHLEN; ++i) {
    run += bf2f(vp[(size_t)i * D_DIM]);
    po[(size_t)i * CONCAT_LD] = f2bf(cf[(size_t)i * H_DIM] * run);
  }
}

// ---- in-place LayerNorm on d_out rows ----
__global__ __launch_bounds__(256) void ln_kernel(
    float* __restrict__ out, const float* __restrict__ gamma, const float* __restrict__ beta) {
  int row = blockIdx.x, t = threadIdx.x;
  float* pr = out + (size_t)row * D_DIM;
  float vals[8];
  float s = 0.f;
#pragma unroll
  for (int i = 0; i < 8; ++i) { vals[i] = pr[t + i * 256]; s += vals[i]; }
  __shared__ float red[4];
  for (int off = 32; off; off >>= 1) s += __shfl_down(s, off);
  if ((t & 63) == 0) red[t >> 6] = s;
  __syncthreads();
  float mean = (red[0] + red[1] + red[2] + red[3]) * (1.f / D_DIM);
  __syncthreads();
  float c2 = 0.f;
#pragma unroll
  for (int i = 0; i < 8; ++i) { float c = vals[i] - mean; c2 += c * c; }
  for (int off = 32; off; off >>= 1) c2 += __shfl_down(c2, off);
  if ((t & 63) == 0) red[t >> 6] = c2;
  __syncthreads();
  float var = (red[0] + red[1] + red[2] + red[3]) * (1.f / D_DIM);
  float rstd = rsqrtf(var + 1e-6f);
#pragma unroll
  for (int i = 0; i < 8; ++i) {
    int col = t + i * 256;
    pr[col] = (vals[i] - mean) * rstd * gamma[col] + beta[col];
  }
}

extern "C" void kernel_launch(void* const* d_in, const int* in_sizes, int n_in,
                              void* d_out, int out_size, void* d_ws, size_t ws_size,
                              hipStream_t stream) {
  const float* x      = (const float*)d_in[0];
  const float* vector = (const float*)d_in[1];
  const float* W_att  = (const float*)d_in[2];
  const float* temp   = (const float*)d_in[3];
  const float* W_val  = (const float*)d_in[4];
  const float* W_op   = (const float*)d_in[5];
  const float* ff1    = (const float*)d_in[6];
  const float* ff1_b  = (const float*)d_in[7];
  const float* ff2    = (const float*)d_in[8];
  const float* ff2_b  = (const float*)d_in[9];
  const float* gamma  = (const float*)d_in[10];
  const float* beta   = (const float*)d_in[11];
  float* out = (float*)d_out;

  char* ws = (char*)d_ws;
  auto alloc = [&](size_t bytes) {
    char* p = ws; ws += (bytes + 255) & ~(size_t)255; return p;
  };
  unsigned short* concat = (unsigned short*)alloc((size_t)M_ROWS * CONCAT_LD * 2);  // [x | pooled]
  unsigned short* wv_t   = (unsigned short*)alloc((size_t)2048 * 2048 * 2);
  unsigned short* btff1  = (unsigned short*)alloc((size_t)2048 * 4096 * 2);  // [F1a^T | Wc^T] rows n, ld 4096
  unsigned short* f1bT   = (unsigned short*)alloc((size_t)2048 * 2048 * 2);
  unsigned short* wop_bf = (unsigned short*)alloc((size_t)2048 * 2048 * 2);
  unsigned short* ff2_t  = (unsigned short*)alloc((size_t)2048 * 2048 * 2);
  unsigned short* vbuf   = (unsigned short*)alloc((size_t)M_ROWS * 2048 * 2);
  unsigned short* h1     = (unsigned short*)alloc((size_t)M_ROWS * 2048 * 2);
  float* logits = (float*)alloc((size_t)M_ROWS * H_DIM * 4);
  float* coef   = (float*)alloc((size_t)M_ROWS * H_DIM * 4);
  float* csum   = (float*)alloc((size_t)B_DIM * NCHUNK * D_DIM * 4);
  float* part   = (float*)alloc((size_t)16 * 4 * 2048 * 4);
  float* bias2  = (float*)alloc((size_t)4 * 2048 * 4);

  xconv_logits_kernel<<<M_ROWS, 256, 0, stream>>>(x, W_att, concat, logits);
  transpose_conv_kernel<<<dim3(64, 64), 256, 0, stream>>>(W_val, wv_t, 2048, 2048, 2048);
  transpose_conv_kernel<<<dim3(64, 64), 256, 0, stream>>>(ff1, btff1, 2048, 2048, 4096);
  transpose_conv_kernel<<<dim3(64, 64), 256, 0, stream>>>(ff1 + (size_t)2048 * 2048, f1bT, 2048, 2048, 2048);
  convert_kernel<<<2048 * 2048 / 1024, 256, 0, stream>>>(W_op, wop_bf);
  transpose_conv_kernel<<<dim3(64, 64), 256, 0, stream>>>(ff2, ff2_t, 2048, 2048, 2048);
  coef_kernel<<<B_DIM * H_DIM, 256, 0, stream>>>(logits, temp, coef);
  // Wc^T[n][i] = (F1b^T @ W_op^T)[n][i] -> btff1[:, 2048:4096]
  gemm_bt_kernel<1><<<dim3(16, 16), 256, 0, stream>>>(
      f1bT, 2048, wop_bf, 2048, 2048, btff1 + 2048, 4096, nullptr, nullptr);
  // bias2 = vector @ F1b + ff1_b
  bias2_partial_kernel<<<dim3(8, 16, 4), 256, 0, stream>>>(vector, ff1, part);
  bias2_reduce_kernel<<<dim3(8, 4), 256, 0, stream>>>(part, ff1_b, bias2);
  // v = x @ W_values
  gemm_bt_kernel<1><<<dim3(16, 64), 256, 0, stream>>>(
      concat, CONCAT_LD, wv_t, 2048, 2048, vbuf, 2048, nullptr, nullptr);
  scan_partial_kernel<<<dim3(8, NCHUNK, B_DIM), 256, 0, stream>>>(vbuf, csum);
  scan_offsets_kernel<<<dim3(8, B_DIM), 256, 0, stream>>>(csum);
  scan_apply_kernel<<<dim3(8, NCHUNK, B_DIM), 256, 0, stream>>>(vbuf, csum, coef, concat + 2048);
  // h1 = relu([x|pooled] @ [F1a;Wc] + bias2[b])
  gemm_bt_kernel<2><<<dim3(16, 64), 256, 0, stream>>>(
      concat, CONCAT_LD, btff1, 4096, 4096, h1, 2048, bias2, nullptr);
  // out = relu(h1 @ ff2 + ff2_b) + x
  gemm_bt_kernel<4><<<dim3(16, 64), 256, 0, stream>>>(
      h1, 2048, ff2_t, 2048, 2048, out, 2048, ff2_b, x);
  ln_kernel<<<M_ROWS, 256, 0, stream>>>(out, gamma, beta);
}